// Round 16
// baseline (276.405 us; speedup 1.0000x reference)
//
#include <hip/hip_runtime.h>
#include <cstddef>

#define SS 1024
#define DF 768
#define NBATCH 16
#define GAT_ALPHA 0.2f

typedef _Float16 f16x8 __attribute__((ext_vector_type(8)));
typedef _Float16 f16x4 __attribute__((ext_vector_type(4)));
typedef float f32x4 __attribute__((ext_vector_type(4)));

// async global->LDS, 16B per lane. LDS dest is wave-uniform base + lane*16.
__device__ __forceinline__ void gload16(const void* g, void* l) {
  __builtin_amdgcn_global_load_lds(
      (const __attribute__((address_space(1))) void*)g,
      (__attribute__((address_space(3))) void*)l, 16, 0, 0);
}

__device__ __forceinline__ float lrelu(float t) {
  return fmaxf(t, GAT_ALPHA * t);
}

// ---------------------------------------------------------------------------
// pre: fused prologue (r14 proven). blocks [0,12288): X f32->f16;
// [12288,13440): W f32->f16; [13440,21632): mask int32 -> bitmask.
// ---------------------------------------------------------------------------
__global__ __launch_bounds__(256) void pre_k(const float* __restrict__ X0,
                                             _Float16* __restrict__ X16,
                                             const float* __restrict__ W,
                                             _Float16* __restrict__ W16,
                                             const int* __restrict__ mask,
                                             unsigned char* __restrict__ bm) {
  const int bid = blockIdx.x;
  if (bid < 13440) {
    const float* in = (bid < 12288) ? X0 : W;
    _Float16* out = (bid < 12288) ? X16 : W16;
    const int base = (bid < 12288) ? bid : (bid - 12288);
    const int idx = (base * 256 + (int)threadIdx.x) * 4;
    float4 v = *(const float4*)&in[idx];
    f16x4 o;
    o[0] = (_Float16)v.x;
    o[1] = (_Float16)v.y;
    o[2] = (_Float16)v.z;
    o[3] = (_Float16)v.w;
    *(f16x4*)&out[idx] = o;
  } else {
    const size_t t = (size_t)(bid - 13440) * 256 + threadIdx.x;  // byte idx
    const int* mp = mask + t * 8;
    const int4 a = *(const int4*)mp;
    const int4 c = *(const int4*)(mp + 4);
    unsigned v = (unsigned)(a.x > 0) | ((unsigned)(a.y > 0) << 1) |
                 ((unsigned)(a.z > 0) << 2) | ((unsigned)(a.w > 0) << 3) |
                 ((unsigned)(c.x > 0) << 4) | ((unsigned)(c.y > 0) << 5) |
                 ((unsigned)(c.z > 0) << 6) | ((unsigned)(c.w > 0) << 7);
    bm[t] = (unsigned char)v;
  }
}

// ===========================================================================
// GEMM1 (r9/r12 proven): 8 waves, BM=128, BN=384, BK=32; 4-slot LDS ring;
// depth-2 prefetch; counted vmcnt(4); ONE barrier per K-tile.
// Epilogue: LDS transpose -> coalesced hT write + fused rowdots partials.
// ===========================================================================
__global__ __launch_bounds__(512, 2) void gemm1_k(
    const _Float16* __restrict__ X16, const _Float16* __restrict__ W16,
    const float* __restrict__ Wbl, const float* __restrict__ Al,
    _Float16* __restrict__ hT16, float* __restrict__ psi2,
    float* __restrict__ psj2) {
  __shared__ __align__(16) char smem[131072];  // 4 slots x 32KB
  const int flat = blockIdx.x;
  const int swz = (flat & 7) * 32 + (flat >> 3);  // XCD-chunked, 256%8==0
  const int m0 = (swz >> 1) * 128;
  const int n0 = (swz & 1) * 384;
  const int tid = threadIdx.x;
  const int w = tid >> 6, lane = tid & 63;

  const int srow = w * 16 + (lane >> 2);
  const int sk8 = ((lane & 3) ^ ((lane >> 3) & 3)) * 8;  // swizzled src chunk
  const int rby = ((lane >> 4) ^ ((lane >> 1) & 3)) * 16;  // swizzled read
  const int rrow = lane & 15;

  f32x4 acc[8][3];
#pragma unroll
  for (int mi = 0; mi < 8; ++mi)
#pragma unroll
    for (int ni = 0; ni < 3; ++ni) acc[mi][ni] = (f32x4)(0.f);

#define STGA1(s, kt)                                                       \
  gload16(&X16[(size_t)(m0 + srow) * DF + (kt) * 32 + sk8],                \
          smem + (s) * 32768 + w * 1024)
#define STGB1(s, kt, q)                                                    \
  gload16(&W16[(size_t)(n0 + (q) * 128 + srow) * DF + (kt) * 32 + sk8],    \
          smem + (s) * 32768 + 8192 + (q) * 8192 + w * 1024)

  const int NT = DF / 32;  // 24
  STGA1(0, 0); STGB1(0, 0, 0); STGB1(0, 0, 1); STGB1(0, 0, 2);
  STGA1(1, 1); STGB1(1, 1, 0); STGB1(1, 1, 1); STGB1(1, 1, 2);
  asm volatile("s_waitcnt vmcnt(4)" ::: "memory");
  asm volatile("s_barrier" ::: "memory");

  for (int t = 0; t < NT; ++t) {
    const int s = t & 3;
    const char* Ab = smem + s * 32768;
    const char* Bb = smem + s * 32768 + 8192;
    f16x8 bfr[3], afr[8];
#pragma unroll
    for (int ni = 0; ni < 3; ++ni)
      bfr[ni] = *(const f16x8*)(Bb + (w * 48 + ni * 16 + rrow) * 64 + rby);
#pragma unroll
    for (int mi = 0; mi < 8; ++mi)
      afr[mi] = *(const f16x8*)(Ab + (mi * 16 + rrow) * 64 + rby);
    if (t + 2 < NT) {
      const int s2 = (t + 2) & 3;
      STGA1(s2, t + 2);
      STGB1(s2, t + 2, 0);
      STGB1(s2, t + 2, 1);
      STGB1(s2, t + 2, 2);
    }
    if (t < NT - 2)
      asm volatile("s_waitcnt vmcnt(4)" ::: "memory");
    else
      asm volatile("s_waitcnt vmcnt(0)" ::: "memory");
    asm volatile("s_barrier" ::: "memory");
    __builtin_amdgcn_s_setprio(1);
#pragma unroll
    for (int mi = 0; mi < 8; ++mi)
#pragma unroll
      for (int ni = 0; ni < 3; ++ni)
        acc[mi][ni] = __builtin_amdgcn_mfma_f32_16x16x32_f16(
            afr[mi], bfr[ni], acc[mi][ni], 0, 0, 0);
    __builtin_amdgcn_s_setprio(0);
  }
#undef STGA1
#undef STGB1

  // ---- epilogue ----
  __syncthreads();
  _Float16* tb = (_Float16*)smem + (size_t)w * 6528;  // per-wave 48x136
  float* asrc = (float*)(smem + 104448);
  float* adst = asrc + 384;
  float* pwsi = adst + 384;
  float* pwsj = pwsi + 1024;

  for (int i = tid; i < 384; i += 512) {
    asrc[i] = Al[n0 + i];
    adst[i] = Al[DF + n0 + i];
  }
  const int cg = lane >> 4, cr = lane & 15;
  float bias[3];
#pragma unroll
  for (int ni = 0; ni < 3; ++ni) bias[ni] = Wbl[n0 + w * 48 + ni * 16 + cr];
#pragma unroll
  for (int mi = 0; mi < 8; ++mi) {
#pragma unroll
    for (int ni = 0; ni < 3; ++ni) {
      f16x4 tv;
#pragma unroll
      for (int r = 0; r < 4; ++r)
        tv[r] = (_Float16)(acc[mi][ni][r] + bias[ni]);
      *(f16x4*)&tb[(ni * 16 + cr) * 136 + mi * 16 + cg * 4] = tv;
    }
  }
  __syncthreads();

  const float* wa = asrc + w * 48;
  const float* wdp = adst + w * 48;
#pragma unroll
  for (int rr = 0; rr < 2; ++rr) {
    const int r = lane + rr * 64;
    float ps = 0.f, pd = 0.f;
#pragma unroll 8
    for (int c = 0; c < 48; ++c) {
      const float hv = (float)tb[c * 136 + r];
      ps = fmaf(hv, wa[c], ps);
      pd = fmaf(hv, wdp[c], pd);
    }
    pwsi[w * 128 + r] = ps;
    pwsj[w * 128 + r] = pd;
  }
  __syncthreads();
  if (tid < 128) {
    float s = 0.f, d2 = 0.f;
#pragma unroll
    for (int ww = 0; ww < 8; ++ww) {
      s += pwsi[ww * 128 + tid];
      d2 += pwsj[ww * 128 + tid];
    }
    const int nt = swz & 1;
    psi2[nt * 16384 + m0 + tid] = s;
    psj2[nt * 16384 + m0 + tid] = d2;
  }

  const int bb = m0 >> 10, s0 = m0 & 1023;
#pragma unroll
  for (int pass = 0; pass < 12; ++pass) {
    const int c = pass * 4 + (lane >> 4);
    f16x8 v = *(const f16x8*)&tb[c * 136 + (lane & 15) * 8];
    *(f16x8*)&hT16[((size_t)bb * DF + n0 + w * 48 + c) * SS + s0 +
                   (lane & 15) * 8] = v;
  }
}

// ===========================================================================
// GEMM2 flash (r12/r13/r14 proven schedule): P computed IN-LOOP, factorized:
//   P = mask ? (si+sjc>=0 ? e^si*c1[j] : e^{0.2si}*c2[j]) : 0
//   c2<0 sentinel = all-masked uniform column (P = 1/1024, mask ignored).
// si read directly from psi2 partial pair.
// ===========================================================================
__global__ __launch_bounds__(512, 2) void gemm2_k(
    const unsigned char* __restrict__ bmk, const float* __restrict__ psi2,
    const uint2* __restrict__ sq_g, const _Float16* __restrict__ hT16,
    float* __restrict__ outl, _Float16* __restrict__ X16n, int writeX) {
  // [0,131072) ring: slot = A-P 8KB + B 24KB ; [131072,139264) sq (8B/j);
  // [139264,157696) mask 128 rows x 144B
  __shared__ __align__(16) char smem[157696];
  const int flat = blockIdx.x;
  const int swz = (flat & 7) * 32 + (flat >> 3);
  const int b = swz >> 4;
  const int i0 = ((swz >> 1) & 7) * 128;
  const int d0 = (swz & 1) * 384;
  const int tid = threadIdx.x;
  const int w = tid >> 6, lane = tid & 63;

  const int srow = w * 16 + (lane >> 2);
  const int sk8 = ((lane & 3) ^ ((lane >> 3) & 3)) * 8;
  const int rby = ((lane >> 4) ^ ((lane >> 1) & 3)) * 16;
  const int rrow = lane & 15;

  const int pr = tid >> 2, pc = tid & 3;  // P-compute: row, 8-j chunk
  const int ppos = pc ^ ((pr >> 1) & 3);  // swizzled write position

  const _Float16* hTb = hT16 + (size_t)b * DF * SS;

  f32x4 acc[8][3];
#pragma unroll
  for (int mi = 0; mi < 8; ++mi)
#pragma unroll
    for (int ni = 0; ni < 3; ++ni) acc[mi][ni] = (f32x4)(0.f);

#define STGB2(s, kt, q)                                                    \
  gload16(&hTb[((size_t)(d0 + (q) * 128 + srow)) * SS + (kt) * 32 + sk8],  \
          smem + (s) * 32768 + 8192 + (q) * 8192 + w * 1024)

  // PCALC: factorized P, all-f16, no transcendental
#define PCALC(sjch, c1h, c2h, mbit)                                        \
  ((c2h) < (_Float16)0.f                                                   \
       ? (_Float16)0.0009765625f                                           \
       : (!(mbit) ? (_Float16)0.f                                          \
                  : ((_Float16)(sih + (sjch)) >= (_Float16)0.f             \
                         ? (_Float16)(e1h * (c1h))                         \
                         : (_Float16)(e2h * (c2h)))))

#define COMPUTE_P(kt, slot)                                                  \
  {                                                                          \
    const unsigned mw =                                                      \
        *(const unsigned*)(smem + 139264 + pr * 144 + (kt) * 4);             \
    const unsigned mb = (mw >> (pc * 8)) & 0xffu;                            \
    const char* sqb = smem + 131072 + (kt) * 256 + pc * 64;                  \
    const f16x8 q0 = *(const f16x8*)(sqb);                                   \
    const f16x8 q1 = *(const f16x8*)(sqb + 16);                              \
    const f16x8 q2 = *(const f16x8*)(sqb + 32);                              \
    const f16x8 q3 = *(const f16x8*)(sqb + 48);                              \
    f16x8 ph;                                                                \
    ph[0] = PCALC(q0[0], q0[1], q0[2], (mb & 1u));                           \
    ph[1] = PCALC(q0[4], q0[5], q0[6], ((mb >> 1) & 1u));                    \
    ph[2] = PCALC(q1[0], q1[1], q1[2], ((mb >> 2) & 1u));                    \
    ph[3] = PCALC(q1[4], q1[5], q1[6], ((mb >> 3) & 1u));                    \
    ph[4] = PCALC(q2[0], q2[1], q2[2], ((mb >> 4) & 1u));                    \
    ph[5] = PCALC(q2[4], q2[5], q2[6], ((mb >> 5) & 1u));                    \
    ph[6] = PCALC(q3[0], q3[1], q3[2], ((mb >> 6) & 1u));                    \
    ph[7] = PCALC(q3[4], q3[5], q3[6], ((mb >> 7) & 1u));                    \
    *(f16x8*)(smem + (slot) * 32768 + pr * 64 + ppos * 16) = ph;             \
  }

  // ---- prologue ----
  const unsigned char* bmb = bmk + ((size_t)b << 17) + ((size_t)i0 << 7);
  const uint4 mg0 = *(const uint4*)(bmb + tid * 32);
  const uint4 mg1 = *(const uint4*)(bmb + tid * 32 + 16);
  // sq: 1024 j x 8B = 8KB; all 512 threads load 16B each
  gload16((const char*)(sq_g + ((size_t)b << 10)) + tid * 16,
          smem + 131072 + w * 1024);
  const float siv =
      psi2[(b << 10) + i0 + pr] + psi2[16384 + (b << 10) + i0 + pr];
  const _Float16 sih = (_Float16)siv;
  const _Float16 e1h = (_Float16)__expf(siv);
  const _Float16 e2h = (_Float16)__expf(0.2f * siv);
  const int NT = SS / 32;  // 32
  STGB2(0, 0, 0); STGB2(0, 0, 1); STGB2(0, 0, 2);
  STGB2(1, 1, 0); STGB2(1, 1, 1); STGB2(1, 1, 2);
  asm volatile("s_waitcnt vmcnt(0)" ::: "memory");
  *(uint4*)(smem + 139264 + pr * 144 + pc * 32) = mg0;
  *(uint4*)(smem + 139264 + pr * 144 + pc * 32 + 16) = mg1;
  asm volatile("s_waitcnt lgkmcnt(0)" ::: "memory");
  asm volatile("s_barrier" ::: "memory");
  COMPUTE_P(0, 0);
  asm volatile("s_waitcnt lgkmcnt(0)" ::: "memory");
  asm volatile("s_barrier" ::: "memory");

  for (int t = 0; t < NT; ++t) {
    const char* Ab = smem + (t & 3) * 32768;
    const char* Bb = Ab + 8192;
    f16x8 bfr[3], afr[8];
#pragma unroll
    for (int ni = 0; ni < 3; ++ni)
      bfr[ni] = *(const f16x8*)(Bb + (w * 48 + ni * 16 + rrow) * 64 + rby);
#pragma unroll
    for (int mi = 0; mi < 8; ++mi)
      afr[mi] = *(const f16x8*)(Ab + (mi * 16 + rrow) * 64 + rby);
    if (t + 1 < NT) COMPUTE_P(t + 1, (t + 1) & 3);
    if (t + 2 < NT) {
      const int s2 = (t + 2) & 3;
      STGB2(s2, t + 2, 0);
      STGB2(s2, t + 2, 1);
      STGB2(s2, t + 2, 2);
    }
    if (t < NT - 2)
      asm volatile("s_waitcnt vmcnt(3) lgkmcnt(0)" ::: "memory");
    else
      asm volatile("s_waitcnt vmcnt(0) lgkmcnt(0)" ::: "memory");
    asm volatile("s_barrier" ::: "memory");
    __builtin_amdgcn_s_setprio(1);
#pragma unroll
    for (int mi = 0; mi < 8; ++mi)
#pragma unroll
      for (int ni = 0; ni < 3; ++ni)
        acc[mi][ni] = __builtin_amdgcn_mfma_f32_16x16x32_f16(
            afr[mi], bfr[ni], acc[mi][ni], 0, 0, 0);
    __builtin_amdgcn_s_setprio(0);
  }
#undef STGB2
#undef COMPUTE_P
#undef PCALC

  const int cg = lane >> 4, cr = lane & 15;
#pragma unroll
  for (int mi = 0; mi < 8; ++mi) {
#pragma unroll
    for (int ni = 0; ni < 3; ++ni) {
      const int d = d0 + w * 48 + ni * 16 + cr;
      const int row0 = i0 + mi * 16 + cg * 4;
#pragma unroll
      for (int r = 0; r < 4; ++r) {
        float v = acc[mi][ni][r];
        size_t o = ((size_t)b * SS + row0 + r) * DF + d;
        outl[o] = v;
        if (writeX) X16n[o] = (_Float16)v;
      }
    }
  }
}

// ---------------------------------------------------------------------------
// colsum (16 chunks): per column j over 128-row group g:
//   S1 = sum_{masked i, si+sjc>=0} e^{si}, S2 = sum_{masked i, <0} e^{0.2 si}
// block (g,b), g<8; thread (jb, half); each covers 64 rows.
// ---------------------------------------------------------------------------
__global__ __launch_bounds__(256) void colsum_k(
    const unsigned char* __restrict__ bm, const float* __restrict__ psi2,
    const float* __restrict__ psj2, const float* __restrict__ Abp,
    float* __restrict__ pden1, float* __restrict__ pden2) {
  const int g = blockIdx.x;  // 0..7
  const int b = blockIdx.y;  // 0..15
  const int t = threadIdx.x;
  const int jb = t & 127;
  const int half = t >> 7;
  const int row0 = (g << 7) + (half << 6);
  const float ab = Abp[0];
  __shared__ float s_si[128], s_e1[128], s_e2[128];
  if (t < 128) {
    const int ridx = (b << 10) + (g << 7) + t;
    const float v = psi2[ridx] + psi2[16384 + ridx];
    s_si[t] = v;
    s_e1[t] = __expf(v);
    s_e2[t] = __expf(0.2f * v);
  }
  __syncthreads();
  float sc[8];
  {
    const int jidx = (b << 10) + jb * 8;
    float4 a0 = *(const float4*)&psj2[jidx];
    float4 a1 = *(const float4*)&psj2[jidx + 4];
    float4 b0 = *(const float4*)&psj2[16384 + jidx];
    float4 b1 = *(const float4*)&psj2[16384 + jidx + 4];
    sc[0] = a0.x + b0.x + ab; sc[1] = a0.y + b0.y + ab;
    sc[2] = a0.z + b0.z + ab; sc[3] = a0.w + b0.w + ab;
    sc[4] = a1.x + b1.x + ab; sc[5] = a1.y + b1.y + ab;
    sc[6] = a1.z + b1.z + ab; sc[7] = a1.w + b1.w + ab;
  }
  float d1[8] = {0.f, 0.f, 0.f, 0.f, 0.f, 0.f, 0.f, 0.f};
  float d2[8] = {0.f, 0.f, 0.f, 0.f, 0.f, 0.f, 0.f, 0.f};
  const unsigned char* bp = bm + ((size_t)b << 17) + ((size_t)row0 << 7) + jb;
#pragma unroll 4
  for (int r = 0; r < 64; ++r) {
    const unsigned m = bp[(size_t)r << 7];
    const int ri = (half << 6) + r;
    const float siv = s_si[ri], e1v = s_e1[ri], e2v = s_e2[ri];
#pragma unroll
    for (int k = 0; k < 8; ++k) {
      if ((m >> k) & 1) {
        if (siv + sc[k] >= 0.f)
          d1[k] += e1v;
        else
          d2[k] += e2v;
      }
    }
  }
  const size_t o = ((size_t)(g * 2 + half)) * 16384 + (b << 10) + jb * 8;
  *(float4*)&pden1[o] = *(float4*)&d1[0];
  *(float4*)&pden1[o + 4] = *(float4*)&d1[4];
  *(float4*)&pden2[o] = *(float4*)&d2[0];
  *(float4*)&pden2[o + 4] = *(float4*)&d2[4];
}

// ---------------------------------------------------------------------------
// colfin: den = e^{sjc}*S1 + e^{0.2sjc}*S2; pack per j (8B):
//   [sjc, c1, c2, 0] halves, c1 = e^{sjc}/den, c2 = e^{0.2sjc}/den;
//   all-masked column -> c2 = -1/1024 sentinel.
// ---------------------------------------------------------------------------
__global__ __launch_bounds__(256) void colfin_k(
    const float* __restrict__ pden1, const float* __restrict__ pden2,
    const float* __restrict__ psj2, const float* __restrict__ Abp,
    uint2* __restrict__ sq) {
  const int idx = blockIdx.x * 256 + threadIdx.x;  // b*1024 + j
  float S1 = 0.f, S2 = 0.f;
#pragma unroll
  for (int c = 0; c < 16; ++c) {
    S1 += pden1[(size_t)c * 16384 + idx];
    S2 += pden2[(size_t)c * 16384 + idx];
  }
  const float sj = psj2[idx] + psj2[16384 + idx] + Abp[0];
  const float A1 = __expf(sj);
  const float A2 = __expf(0.2f * sj);
  const float den = A1 * S1 + A2 * S2;
  _Float16 sjh = (_Float16)sj;
  _Float16 c1h, c2h;
  if (den > 0.f) {
    c1h = (_Float16)(A1 / den);
    c2h = (_Float16)(A2 / den);
  } else {
    c1h = (_Float16)0.f;
    c2h = (_Float16)(-0.0009765625f);
  }
  unsigned short u0, u1, u2;
  __builtin_memcpy(&u0, &sjh, 2);
  __builtin_memcpy(&u1, &c1h, 2);
  __builtin_memcpy(&u2, &c2h, 2);
  uint2 outw;
  outw.x = (unsigned)u0 | ((unsigned)u1 << 16);
  outw.y = (unsigned)u2;
  sq[idx] = outw;
}

// ---------------------------------------------------------------------------
extern "C" void kernel_launch(void* const* d_in, const int* in_sizes, int n_in,
                              void* d_out, int out_size, void* d_ws,
                              size_t ws_size, hipStream_t stream) {
  const float* X0 = (const float*)d_in[0];
  const int* mask = (const int*)d_in[1];
  const float* W = (const float*)d_in[2];
  const float* Wb = (const float*)d_in[3];
  const float* A = (const float*)d_in[4];
  const float* Ab = (const float*)d_in[5];
  float* out = (float*)d_out;

  const size_t BSD = (size_t)NBATCH * SS * DF;  // 12,582,912 elems
  const size_t BSS = (size_t)NBATCH * SS * SS;  // 16,777,216 elems
  const size_t BS = (size_t)NBATCH * SS;        // 16,384 elems

  char* p = (char*)d_ws;
  _Float16* X16 = (_Float16*)p;   p += BSD * 2;                   // 24 MB
  _Float16* hT16 = (_Float16*)p;  p += BSD * 2;                   // 24 MB
  _Float16* W16 = (_Float16*)p;   p += (size_t)2 * DF * DF * 2;   // 2.25 MB
  unsigned char* bmk = (unsigned char*)p; p += BSS / 8;           // 2 MB
  float* psi2 = (float*)p;  p += 2 * BS * 4;   // 128 KB
  float* psj2 = (float*)p;  p += 2 * BS * 4;   // 128 KB
  float* pden1 = (float*)p; p += 16 * BS * 4;  // 1 MB
  float* pden2 = (float*)p; p += 16 * BS * 4;  // 1 MB
  uint2* sq_g = (uint2*)p;  p += BS * 8;       // 8B/j packed (sjc,c1,c2)

  pre_k<<<21632, 256, 0, stream>>>(X0, X16, W, W16, mask, bmk);

  for (int l = 0; l < 2; ++l) {
    gemm1_k<<<256, 512, 0, stream>>>(X16, W16 + (size_t)l * DF * DF,
                                     Wb + (size_t)l * DF,
                                     A + (size_t)l * 2 * DF, hT16, psi2, psj2);
    colsum_k<<<dim3(8, 16), 256, 0, stream>>>(bmk, psi2, psj2, Ab + l, pden1,
                                              pden2);
    colfin_k<<<64, 256, 0, stream>>>(pden1, pden2, psj2, Ab + l, sq_g);
    gemm2_k<<<256, 512, 0, stream>>>(bmk, psi2, sq_g, hT16,
                                     out + (size_t)l * BSD, X16,
                                     (l == 0) ? 1 : 0);
  }
}

// Round 17
// 236.844 us; speedup vs baseline: 1.1670x; 1.1670x over previous
//
#include <hip/hip_runtime.h>
#include <cstddef>

#define SS 1024
#define DF 768
#define NBATCH 16
#define GAT_ALPHA 0.2f

typedef _Float16 f16x8 __attribute__((ext_vector_type(8)));
typedef _Float16 f16x4 __attribute__((ext_vector_type(4)));
typedef float f32x4 __attribute__((ext_vector_type(4)));

// async global->LDS, 16B per lane. LDS dest is wave-uniform base + lane*16.
__device__ __forceinline__ void gload16(const void* g, void* l) {
  __builtin_amdgcn_global_load_lds(
      (const __attribute__((address_space(1))) void*)g,
      (__attribute__((address_space(3))) void*)l, 16, 0, 0);
}

__device__ __forceinline__ float lrelu(float t) {
  return fmaxf(t, GAT_ALPHA * t);
}

// ---------------------------------------------------------------------------
// pre: fused prologue. blocks [0,12288): X f32->f16; [12288,13440): W f32->f16;
// [13440,21632): mask int32 -> bitmask.
// ---------------------------------------------------------------------------
__global__ __launch_bounds__(256) void pre_k(const float* __restrict__ X0,
                                             _Float16* __restrict__ X16,
                                             const float* __restrict__ W,
                                             _Float16* __restrict__ W16,
                                             const int* __restrict__ mask,
                                             unsigned char* __restrict__ bm) {
  const int bid = blockIdx.x;
  if (bid < 13440) {
    const float* in = (bid < 12288) ? X0 : W;
    _Float16* out = (bid < 12288) ? X16 : W16;
    const int base = (bid < 12288) ? bid : (bid - 12288);
    const int idx = (base * 256 + (int)threadIdx.x) * 4;
    float4 v = *(const float4*)&in[idx];
    f16x4 o;
    o[0] = (_Float16)v.x;
    o[1] = (_Float16)v.y;
    o[2] = (_Float16)v.z;
    o[3] = (_Float16)v.w;
    *(f16x4*)&out[idx] = o;
  } else {
    const size_t t = (size_t)(bid - 13440) * 256 + threadIdx.x;  // byte idx
    const int* mp = mask + t * 8;
    const int4 a = *(const int4*)mp;
    const int4 c = *(const int4*)(mp + 4);
    unsigned v = (unsigned)(a.x > 0) | ((unsigned)(a.y > 0) << 1) |
                 ((unsigned)(a.z > 0) << 2) | ((unsigned)(a.w > 0) << 3) |
                 ((unsigned)(c.x > 0) << 4) | ((unsigned)(c.y > 0) << 5) |
                 ((unsigned)(c.z > 0) << 6) | ((unsigned)(c.w > 0) << 7);
    bm[t] = (unsigned char)v;
  }
}

// ===========================================================================
// GEMM1 (r9/r12 proven): 8 waves, BM=128, BN=384, BK=32; 4-slot LDS ring;
// depth-2 prefetch; counted vmcnt(4); ONE barrier per K-tile.
// Epilogue: LDS transpose -> coalesced hT write + fused rowdots partials.
// ===========================================================================
__global__ __launch_bounds__(512, 2) void gemm1_k(
    const _Float16* __restrict__ X16, const _Float16* __restrict__ W16,
    const float* __restrict__ Wbl, const float* __restrict__ Al,
    _Float16* __restrict__ hT16, float* __restrict__ psi2,
    float* __restrict__ psj2) {
  __shared__ __align__(16) char smem[131072];  // 4 slots x 32KB
  const int flat = blockIdx.x;
  const int swz = (flat & 7) * 32 + (flat >> 3);  // XCD-chunked, 256%8==0
  const int m0 = (swz >> 1) * 128;
  const int n0 = (swz & 1) * 384;
  const int tid = threadIdx.x;
  const int w = tid >> 6, lane = tid & 63;

  const int srow = w * 16 + (lane >> 2);
  const int sk8 = ((lane & 3) ^ ((lane >> 3) & 3)) * 8;  // swizzled src chunk
  const int rby = ((lane >> 4) ^ ((lane >> 1) & 3)) * 16;  // swizzled read
  const int rrow = lane & 15;

  f32x4 acc[8][3];
#pragma unroll
  for (int mi = 0; mi < 8; ++mi)
#pragma unroll
    for (int ni = 0; ni < 3; ++ni) acc[mi][ni] = (f32x4)(0.f);

#define STGA1(s, kt)                                                       \
  gload16(&X16[(size_t)(m0 + srow) * DF + (kt) * 32 + sk8],                \
          smem + (s) * 32768 + w * 1024)
#define STGB1(s, kt, q)                                                    \
  gload16(&W16[(size_t)(n0 + (q) * 128 + srow) * DF + (kt) * 32 + sk8],    \
          smem + (s) * 32768 + 8192 + (q) * 8192 + w * 1024)

  const int NT = DF / 32;  // 24
  STGA1(0, 0); STGB1(0, 0, 0); STGB1(0, 0, 1); STGB1(0, 0, 2);
  STGA1(1, 1); STGB1(1, 1, 0); STGB1(1, 1, 1); STGB1(1, 1, 2);
  asm volatile("s_waitcnt vmcnt(4)" ::: "memory");
  asm volatile("s_barrier" ::: "memory");

  for (int t = 0; t < NT; ++t) {
    const int s = t & 3;
    const char* Ab = smem + s * 32768;
    const char* Bb = smem + s * 32768 + 8192;
    f16x8 bfr[3], afr[8];
#pragma unroll
    for (int ni = 0; ni < 3; ++ni)
      bfr[ni] = *(const f16x8*)(Bb + (w * 48 + ni * 16 + rrow) * 64 + rby);
#pragma unroll
    for (int mi = 0; mi < 8; ++mi)
      afr[mi] = *(const f16x8*)(Ab + (mi * 16 + rrow) * 64 + rby);
    if (t + 2 < NT) {
      const int s2 = (t + 2) & 3;
      STGA1(s2, t + 2);
      STGB1(s2, t + 2, 0);
      STGB1(s2, t + 2, 1);
      STGB1(s2, t + 2, 2);
    }
    if (t < NT - 2)
      asm volatile("s_waitcnt vmcnt(4)" ::: "memory");
    else
      asm volatile("s_waitcnt vmcnt(0)" ::: "memory");
    asm volatile("s_barrier" ::: "memory");
    __builtin_amdgcn_s_setprio(1);
#pragma unroll
    for (int mi = 0; mi < 8; ++mi)
#pragma unroll
      for (int ni = 0; ni < 3; ++ni)
        acc[mi][ni] = __builtin_amdgcn_mfma_f32_16x16x32_f16(
            afr[mi], bfr[ni], acc[mi][ni], 0, 0, 0);
    __builtin_amdgcn_s_setprio(0);
  }
#undef STGA1
#undef STGB1

  // ---- epilogue ----
  __syncthreads();
  _Float16* tb = (_Float16*)smem + (size_t)w * 6528;  // per-wave 48x136
  float* asrc = (float*)(smem + 104448);
  float* adst = asrc + 384;
  float* pwsi = adst + 384;
  float* pwsj = pwsi + 1024;

  for (int i = tid; i < 384; i += 512) {
    asrc[i] = Al[n0 + i];
    adst[i] = Al[DF + n0 + i];
  }
  const int cg = lane >> 4, cr = lane & 15;
  float bias[3];
#pragma unroll
  for (int ni = 0; ni < 3; ++ni) bias[ni] = Wbl[n0 + w * 48 + ni * 16 + cr];
#pragma unroll
  for (int mi = 0; mi < 8; ++mi) {
#pragma unroll
    for (int ni = 0; ni < 3; ++ni) {
      f16x4 tv;
#pragma unroll
      for (int r = 0; r < 4; ++r)
        tv[r] = (_Float16)(acc[mi][ni][r] + bias[ni]);
      *(f16x4*)&tb[(ni * 16 + cr) * 136 + mi * 16 + cg * 4] = tv;
    }
  }
  __syncthreads();

  const float* wa = asrc + w * 48;
  const float* wdp = adst + w * 48;
#pragma unroll
  for (int rr = 0; rr < 2; ++rr) {
    const int r = lane + rr * 64;
    float ps = 0.f, pd = 0.f;
#pragma unroll 8
    for (int c = 0; c < 48; ++c) {
      const float hv = (float)tb[c * 136 + r];
      ps = fmaf(hv, wa[c], ps);
      pd = fmaf(hv, wdp[c], pd);
    }
    pwsi[w * 128 + r] = ps;
    pwsj[w * 128 + r] = pd;
  }
  __syncthreads();
  if (tid < 128) {
    float s = 0.f, d2 = 0.f;
#pragma unroll
    for (int ww = 0; ww < 8; ++ww) {
      s += pwsi[ww * 128 + tid];
      d2 += pwsj[ww * 128 + tid];
    }
    const int nt = swz & 1;
    psi2[nt * 16384 + m0 + tid] = s;
    psj2[nt * 16384 + m0 + tid] = d2;
  }

  const int bb = m0 >> 10, s0 = m0 & 1023;
#pragma unroll
  for (int pass = 0; pass < 12; ++pass) {
    const int c = pass * 4 + (lane >> 4);
    f16x8 v = *(const f16x8*)&tb[c * 136 + (lane & 15) * 8];
    *(f16x8*)&hT16[((size_t)bb * DF + n0 + w * 48 + c) * SS + s0 +
                   (lane & 15) * 8] = v;
  }
}

// ===========================================================================
// GEMM2 flash (r12/r13 proven schedule): P computed IN-LOOP, factorized:
//   P = mask ? (si+sjc>=0 ? e^si*c1[j] : e^{0.2si}*c2[j]) : 0
//   c2<0 sentinel = all-masked uniform column (P = 1/1024, mask ignored).
// si read directly from psi2 partial pair.
// ===========================================================================
__global__ __launch_bounds__(512, 2) void gemm2_k(
    const unsigned char* __restrict__ bmk, const float* __restrict__ psi2,
    const uint2* __restrict__ sq_g, const _Float16* __restrict__ hT16,
    float* __restrict__ outl, _Float16* __restrict__ X16n, int writeX) {
  // [0,131072) ring: slot = A-P 8KB + B 24KB ; [131072,139264) sq (8B/j);
  // [139264,157696) mask 128 rows x 144B
  __shared__ __align__(16) char smem[157696];
  const int flat = blockIdx.x;
  const int swz = (flat & 7) * 32 + (flat >> 3);
  const int b = swz >> 4;
  const int i0 = ((swz >> 1) & 7) * 128;
  const int d0 = (swz & 1) * 384;
  const int tid = threadIdx.x;
  const int w = tid >> 6, lane = tid & 63;

  const int srow = w * 16 + (lane >> 2);
  const int sk8 = ((lane & 3) ^ ((lane >> 3) & 3)) * 8;
  const int rby = ((lane >> 4) ^ ((lane >> 1) & 3)) * 16;
  const int rrow = lane & 15;

  const int pr = tid >> 2, pc = tid & 3;  // P-compute: row, 8-j chunk
  const int ppos = pc ^ ((pr >> 1) & 3);  // swizzled write position

  const _Float16* hTb = hT16 + (size_t)b * DF * SS;

  f32x4 acc[8][3];
#pragma unroll
  for (int mi = 0; mi < 8; ++mi)
#pragma unroll
    for (int ni = 0; ni < 3; ++ni) acc[mi][ni] = (f32x4)(0.f);

#define STGB2(s, kt, q)                                                    \
  gload16(&hTb[((size_t)(d0 + (q) * 128 + srow)) * SS + (kt) * 32 + sk8],  \
          smem + (s) * 32768 + 8192 + (q) * 8192 + w * 1024)

  // PCALC: factorized P, all-f16, no transcendental
#define PCALC(sjch, c1h, c2h, mbit)                                        \
  ((c2h) < (_Float16)0.f                                                   \
       ? (_Float16)0.0009765625f                                           \
       : (!(mbit) ? (_Float16)0.f                                          \
                  : ((_Float16)(sih + (sjch)) >= (_Float16)0.f             \
                         ? (_Float16)(e1h * (c1h))                         \
                         : (_Float16)(e2h * (c2h)))))

#define COMPUTE_P(kt, slot)                                                  \
  {                                                                          \
    const unsigned mw =                                                      \
        *(const unsigned*)(smem + 139264 + pr * 144 + (kt) * 4);             \
    const unsigned mb = (mw >> (pc * 8)) & 0xffu;                            \
    const char* sqb = smem + 131072 + (kt) * 256 + pc * 64;                  \
    const f16x8 q0 = *(const f16x8*)(sqb);                                   \
    const f16x8 q1 = *(const f16x8*)(sqb + 16);                              \
    const f16x8 q2 = *(const f16x8*)(sqb + 32);                              \
    const f16x8 q3 = *(const f16x8*)(sqb + 48);                              \
    f16x8 ph;                                                                \
    ph[0] = PCALC(q0[0], q0[1], q0[2], (mb & 1u));                           \
    ph[1] = PCALC(q0[4], q0[5], q0[6], ((mb >> 1) & 1u));                    \
    ph[2] = PCALC(q1[0], q1[1], q1[2], ((mb >> 2) & 1u));                    \
    ph[3] = PCALC(q1[4], q1[5], q1[6], ((mb >> 3) & 1u));                    \
    ph[4] = PCALC(q2[0], q2[1], q2[2], ((mb >> 4) & 1u));                    \
    ph[5] = PCALC(q2[4], q2[5], q2[6], ((mb >> 5) & 1u));                    \
    ph[6] = PCALC(q3[0], q3[1], q3[2], ((mb >> 6) & 1u));                    \
    ph[7] = PCALC(q3[4], q3[5], q3[6], ((mb >> 7) & 1u));                    \
    *(f16x8*)(smem + (slot) * 32768 + pr * 64 + ppos * 16) = ph;             \
  }

  // ---- prologue ----
  const unsigned char* bmb = bmk + ((size_t)b << 17) + ((size_t)i0 << 7);
  const uint4 mg0 = *(const uint4*)(bmb + tid * 32);
  const uint4 mg1 = *(const uint4*)(bmb + tid * 32 + 16);
  // sq: 1024 j x 8B = 8KB; all 512 threads load 16B each
  gload16((const char*)(sq_g + ((size_t)b << 10)) + tid * 16,
          smem + 131072 + w * 1024);
  const float siv =
      psi2[(b << 10) + i0 + pr] + psi2[16384 + (b << 10) + i0 + pr];
  const _Float16 sih = (_Float16)siv;
  const _Float16 e1h = (_Float16)__expf(siv);
  const _Float16 e2h = (_Float16)__expf(0.2f * siv);
  const int NT = SS / 32;  // 32
  STGB2(0, 0, 0); STGB2(0, 0, 1); STGB2(0, 0, 2);
  STGB2(1, 1, 0); STGB2(1, 1, 1); STGB2(1, 1, 2);
  asm volatile("s_waitcnt vmcnt(0)" ::: "memory");
  *(uint4*)(smem + 139264 + pr * 144 + pc * 32) = mg0;
  *(uint4*)(smem + 139264 + pr * 144 + pc * 32 + 16) = mg1;
  asm volatile("s_waitcnt lgkmcnt(0)" ::: "memory");
  asm volatile("s_barrier" ::: "memory");
  COMPUTE_P(0, 0);
  asm volatile("s_waitcnt lgkmcnt(0)" ::: "memory");
  asm volatile("s_barrier" ::: "memory");

  for (int t = 0; t < NT; ++t) {
    const char* Ab = smem + (t & 3) * 32768;
    const char* Bb = Ab + 8192;
    f16x8 bfr[3], afr[8];
#pragma unroll
    for (int ni = 0; ni < 3; ++ni)
      bfr[ni] = *(const f16x8*)(Bb + (w * 48 + ni * 16 + rrow) * 64 + rby);
#pragma unroll
    for (int mi = 0; mi < 8; ++mi)
      afr[mi] = *(const f16x8*)(Ab + (mi * 16 + rrow) * 64 + rby);
    if (t + 1 < NT) COMPUTE_P(t + 1, (t + 1) & 3);
    if (t + 2 < NT) {
      const int s2 = (t + 2) & 3;
      STGB2(s2, t + 2, 0);
      STGB2(s2, t + 2, 1);
      STGB2(s2, t + 2, 2);
    }
    if (t < NT - 2)
      asm volatile("s_waitcnt vmcnt(3) lgkmcnt(0)" ::: "memory");
    else
      asm volatile("s_waitcnt vmcnt(0) lgkmcnt(0)" ::: "memory");
    asm volatile("s_barrier" ::: "memory");
    __builtin_amdgcn_s_setprio(1);
#pragma unroll
    for (int mi = 0; mi < 8; ++mi)
#pragma unroll
      for (int ni = 0; ni < 3; ++ni)
        acc[mi][ni] = __builtin_amdgcn_mfma_f32_16x16x32_f16(
            afr[mi], bfr[ni], acc[mi][ni], 0, 0, 0);
    __builtin_amdgcn_s_setprio(0);
  }
#undef STGB2
#undef COMPUTE_P
#undef PCALC

  const int cg = lane >> 4, cr = lane & 15;
#pragma unroll
  for (int mi = 0; mi < 8; ++mi) {
#pragma unroll
    for (int ni = 0; ni < 3; ++ni) {
      const int d = d0 + w * 48 + ni * 16 + cr;
      const int row0 = i0 + mi * 16 + cg * 4;
#pragma unroll
      for (int r = 0; r < 4; ++r) {
        float v = acc[mi][ni][r];
        size_t o = ((size_t)b * SS + row0 + r) * DF + d;
        outl[o] = v;
        if (writeX) X16n[o] = (_Float16)v;
      }
    }
  }
}

// ---------------------------------------------------------------------------
// colsum (refj-free, reads partials directly): per column j accumulate
//   S1 = sum_{masked i, si+sjc>=0} e^{si}, S2 = sum_{masked i, <0} e^{0.2 si}
// ---------------------------------------------------------------------------
__global__ __launch_bounds__(256) void colsum_k(
    const unsigned char* __restrict__ bm, const float* __restrict__ psi2,
    const float* __restrict__ psj2, const float* __restrict__ Abp,
    float* __restrict__ pden1, float* __restrict__ pden2) {
  const int g = blockIdx.x;  // 0..31
  const int b = blockIdx.y;  // 0..15
  const int t = threadIdx.x;
  const int jb = t & 127;
  const int half = t >> 7;
  const int row0 = (g << 5) + (half << 4);
  const float ab = Abp[0];
  __shared__ float s_si[32], s_e1[32], s_e2[32];
  if (t < 32) {
    const int ridx = (b << 10) + (g << 5) + t;
    const float v = psi2[ridx] + psi2[16384 + ridx];
    s_si[t] = v;
    s_e1[t] = __expf(v);
    s_e2[t] = __expf(0.2f * v);
  }
  __syncthreads();
  float sc[8];
  {
    const int jidx = (b << 10) + jb * 8;
    float4 a0 = *(const float4*)&psj2[jidx];
    float4 a1 = *(const float4*)&psj2[jidx + 4];
    float4 b0 = *(const float4*)&psj2[16384 + jidx];
    float4 b1 = *(const float4*)&psj2[16384 + jidx + 4];
    sc[0] = a0.x + b0.x + ab; sc[1] = a0.y + b0.y + ab;
    sc[2] = a0.z + b0.z + ab; sc[3] = a0.w + b0.w + ab;
    sc[4] = a1.x + b1.x + ab; sc[5] = a1.y + b1.y + ab;
    sc[6] = a1.z + b1.z + ab; sc[7] = a1.w + b1.w + ab;
  }
  float d1[8] = {0.f, 0.f, 0.f, 0.f, 0.f, 0.f, 0.f, 0.f};
  float d2[8] = {0.f, 0.f, 0.f, 0.f, 0.f, 0.f, 0.f, 0.f};
  const unsigned char* bp = bm + ((size_t)b << 17) + ((size_t)row0 << 7) + jb;
#pragma unroll 4
  for (int r = 0; r < 16; ++r) {
    const unsigned m = bp[(size_t)r << 7];
    const int ri = (half << 4) + r;
    const float siv = s_si[ri], e1v = s_e1[ri], e2v = s_e2[ri];
#pragma unroll
    for (int k = 0; k < 8; ++k) {
      if ((m >> k) & 1) {
        if (siv + sc[k] >= 0.f)
          d1[k] += e1v;
        else
          d2[k] += e2v;
      }
    }
  }
  const size_t o = ((size_t)(g * 2 + half)) * 16384 + (b << 10) + jb * 8;
  *(float4*)&pden1[o] = *(float4*)&d1[0];
  *(float4*)&pden1[o + 4] = *(float4*)&d1[4];
  *(float4*)&pden2[o] = *(float4*)&d2[0];
  *(float4*)&pden2[o + 4] = *(float4*)&d2[4];
}

// ---------------------------------------------------------------------------
// colfin (refj-free): den = e^{sjc}*S1 + e^{0.2sjc}*S2; pack per j (8B):
//   [sjc, c1, c2, 0] halves, c1 = e^{sjc}/den, c2 = e^{0.2sjc}/den;
//   all-masked column -> c2 = -1/1024 sentinel.
// ---------------------------------------------------------------------------
__global__ __launch_bounds__(256) void colfin_k(
    const float* __restrict__ pden1, const float* __restrict__ pden2,
    const float* __restrict__ psj2, const float* __restrict__ Abp,
    uint2* __restrict__ sq) {
  const int idx = blockIdx.x * 256 + threadIdx.x;  // b*1024 + j
  float S1 = 0.f, S2 = 0.f;
#pragma unroll
  for (int c = 0; c < 64; ++c) {
    S1 += pden1[(size_t)c * 16384 + idx];
    S2 += pden2[(size_t)c * 16384 + idx];
  }
  const float sj = psj2[idx] + psj2[16384 + idx] + Abp[0];
  const float A1 = __expf(sj);
  const float A2 = __expf(0.2f * sj);
  const float den = A1 * S1 + A2 * S2;
  _Float16 sjh = (_Float16)sj;
  _Float16 c1h, c2h;
  if (den > 0.f) {
    c1h = (_Float16)(A1 / den);
    c2h = (_Float16)(A2 / den);
  } else {
    c1h = (_Float16)0.f;
    c2h = (_Float16)(-0.0009765625f);
  }
  unsigned short u0, u1, u2;
  __builtin_memcpy(&u0, &sjh, 2);
  __builtin_memcpy(&u1, &c1h, 2);
  __builtin_memcpy(&u2, &c2h, 2);
  uint2 outw;
  outw.x = (unsigned)u0 | ((unsigned)u1 << 16);
  outw.y = (unsigned)u2;
  sq[idx] = outw;
}

// ---------------------------------------------------------------------------
extern "C" void kernel_launch(void* const* d_in, const int* in_sizes, int n_in,
                              void* d_out, int out_size, void* d_ws,
                              size_t ws_size, hipStream_t stream) {
  const float* X0 = (const float*)d_in[0];
  const int* mask = (const int*)d_in[1];
  const float* W = (const float*)d_in[2];
  const float* Wb = (const float*)d_in[3];
  const float* A = (const float*)d_in[4];
  const float* Ab = (const float*)d_in[5];
  float* out = (float*)d_out;

  const size_t BSD = (size_t)NBATCH * SS * DF;  // 12,582,912 elems
  const size_t BSS = (size_t)NBATCH * SS * SS;  // 16,777,216 elems
  const size_t BS = (size_t)NBATCH * SS;        // 16,384 elems

  char* p = (char*)d_ws;
  _Float16* X16 = (_Float16*)p;   p += BSD * 2;                   // 24 MB
  _Float16* hT16 = (_Float16*)p;  p += BSD * 2;                   // 24 MB
  _Float16* W16 = (_Float16*)p;   p += (size_t)2 * DF * DF * 2;   // 2.25 MB
  unsigned char* bmk = (unsigned char*)p; p += BSS / 8;           // 2 MB
  float* psi2 = (float*)p;  p += 2 * BS * 4;   // 128 KB
  float* psj2 = (float*)p;  p += 2 * BS * 4;   // 128 KB
  float* pden1 = (float*)p; p += 64 * BS * 4;  // 4 MB
  float* pden2 = (float*)p; p += 64 * BS * 4;  // 4 MB
  uint2* sq_g = (uint2*)p;  p += BS * 8;       // 8B/j packed (sjc,c1,c2)

  pre_k<<<21632, 256, 0, stream>>>(X0, X16, W, W16, mask, bmk);

  for (int l = 0; l < 2; ++l) {
    gemm1_k<<<256, 512, 0, stream>>>(X16, W16 + (size_t)l * DF * DF,
                                     Wb + (size_t)l * DF,
                                     A + (size_t)l * 2 * DF, hT16, psi2, psj2);
    colsum_k<<<dim3(32, 16), 256, 0, stream>>>(bmk, psi2, psj2, Ab + l, pden1,
                                               pden2);
    colfin_k<<<64, 256, 0, stream>>>(pden1, pden2, psj2, Ab + l, sq_g);
    gemm2_k<<<256, 512, 0, stream>>>(bmk, psi2, sq_g, hT16,
                                     out + (size_t)l * BSD, X16,
                                     (l == 0) ? 1 : 0);
  }
}